// Round 6
// baseline (2371.664 us; speedup 1.0000x reference)
//
#include <hip/hip_runtime.h>

// Round 6: barrier-free flash attention. K/V read L2->registers directly as MFMA
// fragments (no LDS staging, no main-loop __syncthreads). Proj emits fragment-tiled
// Q/K/V so every attn global load is a wave-contiguous 1KB dwordx4.
// Block = 512 thr = 8 waves = one 32-q tile x 8 key-ranges (split-K), grid 512
// (2 blocks/CU, 4 waves/SIMD). 8-way merge epilogue. XCD-pinned batches.
//   d_in: 0=x [4,4096,256] f32, 1=mask [4,4096] i32, 2=Wk, 3=Wq, 4=Wv [256,256] f32
// ws (f16): qT [BT/32][8192] | kT [BT/16][4096] | vT [BT/16][4096]
//   qT tile: [(qh*8+kc)*512 + lane*8+j]  <-> Q[q=tile*32+qh*16+(lane&15)][kc*32+(lane>>4)*8+j]
//   kT tile: [kc*512 + key*32 + l4*8+j]  <-> K[key][kc*32+l4*8+j]
//   vT tile: [d*16 + key]                <-> V^T[d][key]

typedef __attribute__((ext_vector_type(8)))  _Float16 f16x8;
typedef __attribute__((ext_vector_type(4)))  _Float16 f16x4;
typedef __attribute__((ext_vector_type(4)))  float    f32x4;
typedef __attribute__((ext_vector_type(16))) float    f32x16;

constexpr int Bb = 4;
constexpr int Tt = 4096;
constexpr int Cc = 256;
constexpr int BT = Bb * Tt;

#define MFMA16(a, b, c) __builtin_amdgcn_mfma_f32_16x16x32_f16((a), (b), (c), 0, 0, 0)
#define MFMA32(a, b, c) __builtin_amdgcn_mfma_f32_32x32x16_f16((a), (b), (c), 0, 0, 0)

// ---------------- Kernel A: fused QKV projection (y = x @ W^T), tiled stores ----
__global__ __launch_bounds__(256) void qkv_proj(
    const float* __restrict__ x,
    const float* __restrict__ Wq, const float* __restrict__ Wk,
    const float* __restrict__ Wv,
    _Float16* __restrict__ qo, _Float16* __restrict__ ko,
    _Float16* __restrict__ vto)
{
    extern __shared__ _Float16 sm[];
    _Float16* xs = sm;              // [128][264]
    _Float16* wsm = sm + 128 * 264; // [128][264]

    const int tid = threadIdx.x;
    const int m0  = blockIdx.x * 128;
    const int ny  = blockIdx.y;
    const int mat = ny >> 1;              // 0=q 1=k 2=v
    const int d0  = (ny & 1) * 128;
    const float* W = (mat == 0) ? Wq : (mat == 1 ? Wk : Wv);

#pragma unroll
    for (int i = 0; i < 32; ++i) {
        int flat = i * 256 + tid;
        int r = flat >> 6, c4 = (flat & 63) << 2;
        float4 v = *reinterpret_cast<const float4*>(x + (size_t)(m0 + r) * Cc + c4);
        f16x4 h = { (_Float16)v.x, (_Float16)v.y, (_Float16)v.z, (_Float16)v.w };
        *reinterpret_cast<f16x4*>(xs + r * 264 + c4) = h;
    }
#pragma unroll
    for (int i = 0; i < 32; ++i) {
        int flat = i * 256 + tid;
        int r = flat >> 6, c4 = (flat & 63) << 2;
        float4 v = *reinterpret_cast<const float4*>(W + (size_t)(d0 + r) * Cc + c4);
        f16x4 h = { (_Float16)v.x, (_Float16)v.y, (_Float16)v.z, (_Float16)v.w };
        *reinterpret_cast<f16x4*>(wsm + r * 264 + c4) = h;
    }
    __syncthreads();

    const int w = tid >> 6, lane = tid & 63;
    const int lr = lane & 15, lg = lane >> 4;

    f32x4 acc[2][8] = {};

#pragma unroll
    for (int kc = 0; kc < 8; ++kc) {
        const int c0 = kc * 32 + lg * 8;
        f16x8 xf[2], wf[8];
#pragma unroll
        for (int mb = 0; mb < 2; ++mb)
            xf[mb] = *reinterpret_cast<const f16x8*>(xs + (w * 32 + mb * 16 + lr) * 264 + c0);
#pragma unroll
        for (int db = 0; db < 8; ++db)
            wf[db] = *reinterpret_cast<const f16x8*>(wsm + (db * 16 + lr) * 264 + c0);
        if (mat != 2) {
#pragma unroll
            for (int mb = 0; mb < 2; ++mb)
#pragma unroll
                for (int db = 0; db < 8; ++db)
                    acc[mb][db] = MFMA16(wf[db], xf[mb], acc[mb][db]);   // D[d][m]
        } else {
#pragma unroll
            for (int mb = 0; mb < 2; ++mb)
#pragma unroll
                for (int db = 0; db < 8; ++db)
                    acc[mb][db] = MFMA16(xf[mb], wf[db], acc[mb][db]);   // D[m][d]
        }
    }

    if (mat != 2) {
        // lane holds 4 consecutive c (=d) for fixed row m: fragment-tiled stores
        const float sc = (mat == 0) ? 0.0625f : 1.0f;
        const int jj  = (lg & 1) * 4;
#pragma unroll
        for (int mb = 0; mb < 2; ++mb)
#pragma unroll
            for (int db = 0; db < 8; ++db) {
                int m  = m0 + w * 32 + mb * 16 + lr;
                int c  = d0 + db * 16 + lg * 4;
                int kc = c >> 5;
                int l4c = (c >> 3) & 3;
                f32x4 a = acc[mb][db];
                f16x4 h = { (_Float16)(a.x * sc), (_Float16)(a.y * sc),
                            (_Float16)(a.z * sc), (_Float16)(a.w * sc) };
                if (mat == 0) {
                    size_t off = (size_t)(m >> 5) * 8192 + (((m >> 4) & 1) * 8 + kc) * 512
                               + l4c * 128 + (m & 15) * 8 + jj;
                    *reinterpret_cast<f16x4*>(qo + off) = h;
                } else {
                    size_t off = (size_t)(m >> 4) * 4096 + kc * 512
                               + (m & 15) * 32 + l4c * 8 + jj;
                    *reinterpret_cast<f16x4*>(ko + off) = h;
                }
            }
    } else {
        // lane holds 4 consecutive keys m..m+3 for fixed d: vT[d][key] tiled
#pragma unroll
        for (int mb = 0; mb < 2; ++mb)
#pragma unroll
            for (int db = 0; db < 8; ++db) {
                int d = d0 + db * 16 + lr;
                int m = m0 + w * 32 + mb * 16 + lg * 4;
                f32x4 a = acc[mb][db];
                f16x4 h = { (_Float16)a.x, (_Float16)a.y, (_Float16)a.z, (_Float16)a.w };
                size_t off = (size_t)(m >> 4) * 4096 + d * 16 + (m & 15);
                *reinterpret_cast<f16x4*>(vto + off) = h;
            }
    }
}

// ---------------- Kernel B: barrier-free flash attention ----------------
__global__ __launch_bounds__(512, 4) void attn_kernel(
    const _Float16* __restrict__ qb, const _Float16* __restrict__ kb,
    const _Float16* __restrict__ vtb, const int* __restrict__ mask,
    float* __restrict__ outp)
{
    __shared__ _Float16 pqs[8][768];        // per-wave P bounce [32 q][24]
    __shared__ float mex[8 * 33], lex[8 * 33];
    __shared__ float buf[8 * 1088];         // merge: [8 w][32 q][34]

    const int tid = threadIdx.x, w = tid >> 6, lane = tid & 63;
    const int l15 = lane & 15, l4 = lane >> 4;
    const int l31 = lane & 31, l5 = lane >> 5;

    const int bid = blockIdx.x;
    const int b   = (bid & 7) >> 1;                    // batch -> XCD pair (L2-resident K/V)
    const int qt  = ((bid >> 3) << 1) | (bid & 1);     // [0,128)
    const int q0  = qt * 32;
    const size_t base = (size_t)b * Tt * Cc;
    const int* maskb = mask + (size_t)b * Tt;
    const _Float16* kTb = kb + base;
    const _Float16* vTb = vtb + base;

    // Q fragments (B-operand): Q[q0 + qh*16 + l15][kc*32 + l4*8 + j], pre-scaled
    f16x8 qf[2][8];
    {
        const _Float16* qTb = qb + base + (size_t)qt * 8192;
#pragma unroll
        for (int qh = 0; qh < 2; ++qh)
#pragma unroll
            for (int kc = 0; kc < 8; ++kc)
                qf[qh][kc] = *reinterpret_cast<const f16x8*>(
                    qTb + (qh * 8 + kc) * 512 + lane * 8);
    }

    f32x16 o[8] = {};                  // O^T[d = dt*32 + (r&3)+8*(r>>2)+4*l5][q = l31]
    float m0r = -60.f, m1r = -60.f, l0r = 0.f, l1r = 0.f;
    _Float16* pw = &pqs[w][0];

    auto LOADT = [&](f16x8 (&kr)[8], f16x8 (&vr)[8], int4& mc, int kt) {
        const _Float16* kp = kTb + (size_t)kt * 4096 + l15 * 32 + l4 * 8;
#pragma unroll
        for (int kc = 0; kc < 8; ++kc)
            kr[kc] = *reinterpret_cast<const f16x8*>(kp + kc * 512);
        const _Float16* vp = vTb + (size_t)kt * 4096 + l31 * 16 + l5 * 8;
#pragma unroll
        for (int dt = 0; dt < 8; ++dt)
            vr[dt] = *reinterpret_cast<const f16x8*>(vp + dt * 512);
        mc = *reinterpret_cast<const int4*>(maskb + kt * 16 + l4 * 4);
    };

    auto COMPUTE = [&](f16x8 (&kr)[8], f16x8 (&vr)[8], int4 mc) {
        // S^T = K Q^T : D[key = l4*4 + r][q = qh*16 + l15]
        f32x4 s40 = { 0.f, 0.f, 0.f, 0.f }, s41 = { 0.f, 0.f, 0.f, 0.f };
#pragma unroll
        for (int kc = 0; kc < 8; ++kc) {
            s40 = MFMA16(kr[kc], qf[0][kc], s40);
            s41 = MFMA16(kr[kc], qf[1][kc], s41);
        }
        if (mc.x == 0) { s40[0] = -1e30f; s41[0] = -1e30f; }
        if (mc.y == 0) { s40[1] = -1e30f; s41[1] = -1e30f; }
        if (mc.z == 0) { s40[2] = -1e30f; s41[2] = -1e30f; }
        if (mc.w == 0) { s40[3] = -1e30f; s41[3] = -1e30f; }

        float t0 = fmaxf(fmaxf(s40[0], s40[1]), fmaxf(s40[2], s40[3]));
        float t1 = fmaxf(fmaxf(s41[0], s41[1]), fmaxf(s41[2], s41[3]));
        t0 = fmaxf(t0, __shfl_xor(t0, 16, 64)); t0 = fmaxf(t0, __shfl_xor(t0, 32, 64));
        t1 = fmaxf(t1, __shfl_xor(t1, 16, 64)); t1 = fmaxf(t1, __shfl_xor(t1, 32, 64));

        if (__any(t0 > m0r + 8.f || t1 > m1r + 8.f)) {     // defer-max
            float mn0 = fmaxf(m0r, t0), mn1 = fmaxf(m1r, t1);
            float c0 = __expf(m0r - mn0), c1 = __expf(m1r - mn1);
            m0r = mn0; m1r = mn1; l0r *= c0; l1r *= c1;
            float cs = (lane & 16) ? c1 : c0;
#pragma unroll
            for (int dt = 0; dt < 8; ++dt) o[dt] *= cs;
        }

        float rs0 = 0.f, rs1 = 0.f;
#pragma unroll
        for (int r = 0; r < 4; ++r) {
            float p0 = __expf(s40[r] - m0r); s40[r] = p0; rs0 += p0;
            float p1 = __expf(s41[r] - m1r); s41[r] = p1; rs1 += p1;
        }
        rs0 += __shfl_xor(rs0, 16, 64); rs0 += __shfl_xor(rs0, 32, 64);
        rs1 += __shfl_xor(rs1, 16, 64); rs1 += __shfl_xor(rs1, 32, 64);
        l0r += rs0; l1r += rs1;

        // P^T -> pw[q][k] (f16), reread as 32x32 B-frag (in-wave RAW, lgkm-ordered)
        f16x4 h0 = { (_Float16)s40[0], (_Float16)s40[1], (_Float16)s40[2], (_Float16)s40[3] };
        f16x4 h1 = { (_Float16)s41[0], (_Float16)s41[1], (_Float16)s41[2], (_Float16)s41[3] };
        *reinterpret_cast<f16x4*>(pw + l15 * 24 + l4 * 4)        = h0;
        *reinterpret_cast<f16x4*>(pw + (16 + l15) * 24 + l4 * 4) = h1;
        f16x8 pf = *reinterpret_cast<const f16x8*>(pw + l31 * 24 + l5 * 8);

        // O^T += V^T P^T (A-frag vr straight from global)
#pragma unroll
        for (int dt = 0; dt < 8; ++dt)
            o[dt] = MFMA32(vr[dt], pf, o[dt]);
    };

    // main loop: 32 tiles of 16 keys, ping-pong register prefetch, NO barriers
    f16x8 kA[8], vA[8], kB[8], vB[8];
    int4 mA_, mB_;
    const int ktb = w * 32;                 // this wave's key-range: tiles [ktb, ktb+32)
    LOADT(kA, vA, mA_, ktb);
#pragma unroll 1
    for (int t2 = 0; t2 < 16; ++t2) {
        LOADT(kB, vB, mB_, ktb + 2 * t2 + 1);
        COMPUTE(kA, vA, mA_);
        LOADT(kA, vA, mA_, (2 * t2 + 2 < 32) ? (ktb + 2 * t2 + 2) : ktb);  // last: dummy
        COMPUTE(kB, vB, mB_);
    }

    // ---- epilogue: 8-way split-K merge ----
    if (l4 == 0) {
        mex[w * 33 + l15] = m0r;  mex[w * 33 + 16 + l15] = m1r;
        lex[w * 33 + l15] = l0r;  lex[w * 33 + 16 + l15] = l1r;
    }
    __syncthreads();

    float mst = -1e30f;
#pragma unroll
    for (int w2 = 0; w2 < 8; ++w2) mst = fmaxf(mst, mex[w2 * 33 + l31]);
    float lt = 0.f;
#pragma unroll
    for (int w2 = 0; w2 < 8; ++w2) lt += lex[w2 * 33 + l31] * __expf(mex[w2 * 33 + l31] - mst);
    float myM = (lane & 16) ? m1r : m0r;
    float eW  = __expf(myM - mst) / lt;

    const int qq = tid >> 4, dd = (tid & 15) * 2;
#pragma unroll 1
    for (int dt = 0; dt < 8; ++dt) {
#pragma unroll
        for (int r = 0; r < 16; ++r) {
            int dloc = (r & 3) + 8 * (r >> 2) + 4 * l5;
            buf[w * 1088 + l31 * 34 + dloc] = o[dt][r] * eW;
        }
        __syncthreads();
        float s0 = 0.f, s1 = 0.f;
#pragma unroll
        for (int w2 = 0; w2 < 8; ++w2) {
            s0 += buf[w2 * 1088 + qq * 34 + dd];
            s1 += buf[w2 * 1088 + qq * 34 + dd + 1];
        }
        *reinterpret_cast<float2*>(
            outp + base + (size_t)(q0 + qq) * Cc + dt * 32 + dd) = make_float2(s0, s1);
        __syncthreads();
    }
}

extern "C" void kernel_launch(void* const* d_in, const int* in_sizes, int n_in,
                              void* d_out, int out_size, void* d_ws, size_t ws_size,
                              hipStream_t stream)
{
    (void)in_sizes; (void)n_in; (void)out_size; (void)ws_size;
    const float* x   = (const float*)d_in[0];
    const int*  mask = (const int*)d_in[1];
    const float* Wk  = (const float*)d_in[2];
    const float* Wq  = (const float*)d_in[3];
    const float* Wv  = (const float*)d_in[4];
    float* out = (float*)d_out;

    _Float16* q  = (_Float16*)d_ws;
    _Float16* k  = q + (size_t)BT * Cc;
    _Float16* vt = k + (size_t)BT * Cc;

    dim3 gA(128, 6), blkA(256);
    size_t ldsA = (size_t)(128 + 128) * 264 * sizeof(_Float16);
    qkv_proj<<<gA, blkA, ldsA, stream>>>(x, Wq, Wk, Wv, q, k, vt);

    dim3 gB(512), blkB(512);
    attn_kernel<<<gB, blkB, 0, stream>>>(q, k, vt, mask, out);
}

// Round 7
// 141.523 us; speedup vs baseline: 16.7581x; 16.7581x over previous
//
#include <hip/hip_runtime.h>

// Round 7: q_w=32 LDS-staged flash attention.
// grid 256 (1 blk/CU), 512 thr = 8 warps = 2 qw(32q) x 4 g(16-key groups).
// K/V double-buffered LDS via linear global_load_lds (proj emits fragment-tiled
// layouts); ONE barrier/iter; QK 16x16 shared-kf, PV 32x32; LDS P-bounce;
// defer-max; 4-way split-K merge epilogue in LDS.
//   d_in: 0=x f32, 1=mask i32, 2=Wk, 3=Wq, 4=Wv
// ws (f16): qT [BT/32][8192] | kT [BT/16][4096] | vT [BT/16][4096]
//   qT: [(qh*8+kc)*512 + lane*8+j] <-> Q[32t+qh*16+(l&15)][kc*32+(l>>4)*8+j] (x1/16)
//   kT: [kc*512 + key*32 + l4*8+j] <-> K[16t+key][kc*32+l4*8+j]
//   vT: [d*16 + key]               <-> V^T[d][16t+key]

typedef __attribute__((ext_vector_type(8)))  _Float16 f16x8;
typedef __attribute__((ext_vector_type(4)))  _Float16 f16x4;
typedef __attribute__((ext_vector_type(4)))  float    f32x4;
typedef __attribute__((ext_vector_type(16))) float    f32x16;

constexpr int Bb = 4;
constexpr int Tt = 4096;
constexpr int Cc = 256;
constexpr int BT = Bb * Tt;
constexpr int NI = 64;                 // iters: 4 groups x 16 keys x 64 = 4096

#define MFMA16(a, b, c) __builtin_amdgcn_mfma_f32_16x16x32_f16((a), (b), (c), 0, 0, 0)
#define MFMA32(a, b, c) __builtin_amdgcn_mfma_f32_32x32x16_f16((a), (b), (c), 0, 0, 0)

__device__ __forceinline__ void gl16(const _Float16* gp, char* lp) {
    __builtin_amdgcn_global_load_lds(
        (const __attribute__((address_space(1))) void*)gp,
        (__attribute__((address_space(3))) void*)lp, 16, 0, 0);
}

// ---------------- Kernel A: fused QKV projection (verbatim round 6) ----------
__global__ __launch_bounds__(256) void qkv_proj(
    const float* __restrict__ x,
    const float* __restrict__ Wq, const float* __restrict__ Wk,
    const float* __restrict__ Wv,
    _Float16* __restrict__ qo, _Float16* __restrict__ ko,
    _Float16* __restrict__ vto)
{
    extern __shared__ _Float16 sm[];
    _Float16* xs = sm;              // [128][264]
    _Float16* wsm = sm + 128 * 264; // [128][264]

    const int tid = threadIdx.x;
    const int m0  = blockIdx.x * 128;
    const int ny  = blockIdx.y;
    const int mat = ny >> 1;              // 0=q 1=k 2=v
    const int d0  = (ny & 1) * 128;
    const float* W = (mat == 0) ? Wq : (mat == 1 ? Wk : Wv);

#pragma unroll
    for (int i = 0; i < 32; ++i) {
        int flat = i * 256 + tid;
        int r = flat >> 6, c4 = (flat & 63) << 2;
        float4 v = *reinterpret_cast<const float4*>(x + (size_t)(m0 + r) * Cc + c4);
        f16x4 h = { (_Float16)v.x, (_Float16)v.y, (_Float16)v.z, (_Float16)v.w };
        *reinterpret_cast<f16x4*>(xs + r * 264 + c4) = h;
    }
#pragma unroll
    for (int i = 0; i < 32; ++i) {
        int flat = i * 256 + tid;
        int r = flat >> 6, c4 = (flat & 63) << 2;
        float4 v = *reinterpret_cast<const float4*>(W + (size_t)(d0 + r) * Cc + c4);
        f16x4 h = { (_Float16)v.x, (_Float16)v.y, (_Float16)v.z, (_Float16)v.w };
        *reinterpret_cast<f16x4*>(wsm + r * 264 + c4) = h;
    }
    __syncthreads();

    const int w = tid >> 6, lane = tid & 63;
    const int lr = lane & 15, lg = lane >> 4;

    f32x4 acc[2][8] = {};

#pragma unroll
    for (int kc = 0; kc < 8; ++kc) {
        const int c0 = kc * 32 + lg * 8;
        f16x8 xf[2], wf[8];
#pragma unroll
        for (int mb = 0; mb < 2; ++mb)
            xf[mb] = *reinterpret_cast<const f16x8*>(xs + (w * 32 + mb * 16 + lr) * 264 + c0);
#pragma unroll
        for (int db = 0; db < 8; ++db)
            wf[db] = *reinterpret_cast<const f16x8*>(wsm + (db * 16 + lr) * 264 + c0);
        if (mat != 2) {
#pragma unroll
            for (int mb = 0; mb < 2; ++mb)
#pragma unroll
                for (int db = 0; db < 8; ++db)
                    acc[mb][db] = MFMA16(wf[db], xf[mb], acc[mb][db]);   // D[d][m]
        } else {
#pragma unroll
            for (int mb = 0; mb < 2; ++mb)
#pragma unroll
                for (int db = 0; db < 8; ++db)
                    acc[mb][db] = MFMA16(xf[mb], wf[db], acc[mb][db]);   // D[m][d]
        }
    }

    if (mat != 2) {
        const float sc = (mat == 0) ? 0.0625f : 1.0f;
        const int jj  = (lg & 1) * 4;
#pragma unroll
        for (int mb = 0; mb < 2; ++mb)
#pragma unroll
            for (int db = 0; db < 8; ++db) {
                int m  = m0 + w * 32 + mb * 16 + lr;
                int c  = d0 + db * 16 + lg * 4;
                int kc = c >> 5;
                int l4c = (c >> 3) & 3;
                f32x4 a = acc[mb][db];
                f16x4 h = { (_Float16)(a.x * sc), (_Float16)(a.y * sc),
                            (_Float16)(a.z * sc), (_Float16)(a.w * sc) };
                if (mat == 0) {
                    size_t off = (size_t)(m >> 5) * 8192 + (((m >> 4) & 1) * 8 + kc) * 512
                               + l4c * 128 + (m & 15) * 8 + jj;
                    *reinterpret_cast<f16x4*>(qo + off) = h;
                } else {
                    size_t off = (size_t)(m >> 4) * 4096 + kc * 512
                               + (m & 15) * 32 + l4c * 8 + jj;
                    *reinterpret_cast<f16x4*>(ko + off) = h;
                }
            }
    } else {
#pragma unroll
        for (int mb = 0; mb < 2; ++mb)
#pragma unroll
            for (int db = 0; db < 8; ++db) {
                int d = d0 + db * 16 + lr;
                int m = m0 + w * 32 + mb * 16 + lg * 4;
                f32x4 a = acc[mb][db];
                f16x4 h = { (_Float16)a.x, (_Float16)a.y, (_Float16)a.z, (_Float16)a.w };
                size_t off = (size_t)(m >> 4) * 4096 + d * 16 + (m & 15);
                *reinterpret_cast<f16x4*>(vto + off) = h;
            }
    }
}

// ---------------- Kernel B: flash attention ----------------
// LDS map (bytes): [0,131072)   2 x [4 g][K 8KB | V 8KB] double buffer
//                  [131072,143360) per-warp P [8][32][24] f16
//                  [143360,144384) mex f32[2][4][32]; [144384,145408) lex
// epilogue reuses [0,132096) as oex f32[4][32][258]
__global__ __launch_bounds__(512, 2) void attn_kernel(
    const _Float16* __restrict__ qb, const _Float16* __restrict__ kb,
    const _Float16* __restrict__ vtb, const int* __restrict__ mask,
    float* __restrict__ outp)
{
    extern __shared__ char smraw[];
    float* mex32 = (float*)(smraw + 143360);
    float* lex32 = (float*)(smraw + 144384);
    float* oexf  = (float*)smraw;

    const int tid = threadIdx.x, w = tid >> 6, lane = tid & 63;
    const int qw = w >> 2, g = w & 3;
    const int l15 = lane & 15, l4 = lane >> 4;
    const int l31 = lane & 31, l5 = lane >> 5;

    const int bid = blockIdx.x;
    const int b   = (bid & 7) >> 1;                    // batch -> XCD pair
    const int qt  = ((bid >> 3) << 1) | (bid & 1);     // [0,64)
    const int q0  = qt * 64;
    const size_t base = (size_t)b * Tt * Cc;
    const int* maskb = mask + (size_t)b * Tt;
    const _Float16* kTb = kb + base;
    const _Float16* vTb = vtb + base;

    // Q fragments: Q[q0 + qw*32 + qh*16 + l15][kc*32 + l4*8 + j]
    f16x8 qf[2][8];
    {
        const _Float16* qTb = qb + (size_t)(b * 128 + qt * 2 + qw) * 8192;
#pragma unroll
        for (int qh = 0; qh < 2; ++qh)
#pragma unroll
            for (int kc = 0; kc < 8; ++kc)
                qf[qh][kc] = *reinterpret_cast<const f16x8*>(
                    qTb + (qh * 8 + kc) * 512 + lane * 8);
    }

    _Float16* pw = (_Float16*)(smraw + 131072) + w * 768;   // [32][24]

    f32x16 o[8] = {};                  // O^T[d = dt*32+(r&3)+8*(r>>2)+4*l5][q=l31]
    float m0r = -60.f, m1r = -60.f, l0r = 0.f, l1r = 0.f;

    // staging: warp (qw,g): qw0 -> K of group g, qw1 -> V of group g (linear copy)
    auto STAGE = [&](int i, int buf) {
        const int kt = i * 4 + g;
        char* dst = smraw + buf * 65536 + g * 16384 + (qw ? 8192 : 0);
        const _Float16* src = (qw ? vTb : kTb) + (size_t)kt * 4096 + lane * 8;
#pragma unroll
        for (int j = 0; j < 8; ++j)
            gl16(src + j * 512, dst + j * 1024);
    };

    STAGE(0, 0);
    asm volatile("s_waitcnt vmcnt(0)" ::: "memory");

    int cur = 0;
#pragma unroll 1
    for (int i = 0; i < NI; ++i) {
        __syncthreads();                       // everyone at iter i; buf cur ready
        if (i + 1 < NI) STAGE(i + 1, cur ^ 1); // flies under compute

        const _Float16* kb_ = (const _Float16*)(smraw + cur * 65536 + g * 16384);
        const _Float16* vb_ = kb_ + 4096;
        int4 mc = *reinterpret_cast<const int4*>(maskb + (i * 4 + g) * 16 + l4 * 4);

        // S^T = K Q^T : D[key = l4*4 + r][q = qh*16 + l15]
        f32x4 s40 = { 0.f, 0.f, 0.f, 0.f }, s41 = { 0.f, 0.f, 0.f, 0.f };
        __builtin_amdgcn_s_setprio(1);
#pragma unroll
        for (int kc = 0; kc < 8; ++kc) {
            f16x8 kf = *reinterpret_cast<const f16x8*>(kb_ + kc * 512 + l15 * 32 + l4 * 8);
            s40 = MFMA16(kf, qf[0][kc], s40);
            s41 = MFMA16(kf, qf[1][kc], s41);
        }
        __builtin_amdgcn_s_setprio(0);

        if (mc.x == 0) { s40[0] = -1e30f; s41[0] = -1e30f; }
        if (mc.y == 0) { s40[1] = -1e30f; s41[1] = -1e30f; }
        if (mc.z == 0) { s40[2] = -1e30f; s41[2] = -1e30f; }
        if (mc.w == 0) { s40[3] = -1e30f; s41[3] = -1e30f; }

        // online softmax per qh (q = l15; keys across l4 groups)
        float t0 = fmaxf(fmaxf(s40[0], s40[1]), fmaxf(s40[2], s40[3]));
        float t1 = fmaxf(fmaxf(s41[0], s41[1]), fmaxf(s41[2], s41[3]));
        t0 = fmaxf(t0, __shfl_xor(t0, 16, 64)); t0 = fmaxf(t0, __shfl_xor(t0, 32, 64));
        t1 = fmaxf(t1, __shfl_xor(t1, 16, 64)); t1 = fmaxf(t1, __shfl_xor(t1, 32, 64));

        if (__any(t0 > m0r + 8.f || t1 > m1r + 8.f)) {     // defer-max
            float mn0 = fmaxf(m0r, t0), mn1 = fmaxf(m1r, t1);
            float c0 = __expf(m0r - mn0), c1 = __expf(m1r - mn1);
            m0r = mn0; m1r = mn1; l0r *= c0; l1r *= c1;
            float cs = (lane & 16) ? c1 : c0;              // o cols: q = l31
#pragma unroll
            for (int dt = 0; dt < 8; ++dt) o[dt] *= cs;
        }

        float rs0 = 0.f, rs1 = 0.f;
#pragma unroll
        for (int r = 0; r < 4; ++r) {
            float p0 = __expf(s40[r] - m0r); s40[r] = p0; rs0 += p0;
            float p1 = __expf(s41[r] - m1r); s41[r] = p1; rs1 += p1;
        }
        rs0 += __shfl_xor(rs0, 16, 64); rs0 += __shfl_xor(rs0, 32, 64);
        rs1 += __shfl_xor(rs1, 16, 64); rs1 += __shfl_xor(rs1, 32, 64);
        l0r += rs0; l1r += rs1;

        // P -> pw[q][k] f16; reread as PV B-frag (in-wave RAW, lgkm-ordered)
        {
            f16x4 h0 = { (_Float16)s40[0], (_Float16)s40[1], (_Float16)s40[2], (_Float16)s40[3] };
            f16x4 h1 = { (_Float16)s41[0], (_Float16)s41[1], (_Float16)s41[2], (_Float16)s41[3] };
            *reinterpret_cast<f16x4*>(pw + l15 * 24 + l4 * 4)        = h0;
            *reinterpret_cast<f16x4*>(pw + (16 + l15) * 24 + l4 * 4) = h1;
        }
        f16x8 pf = *reinterpret_cast<const f16x8*>(pw + l31 * 24 + l5 * 8);

        // O^T += V^T P^T  (32x32x16, K=16 keys)
        __builtin_amdgcn_s_setprio(1);
#pragma unroll
        for (int dt = 0; dt < 8; ++dt) {
            f16x8 vf = *reinterpret_cast<const f16x8*>(vb_ + dt * 512 + l31 * 16 + l5 * 8);
            o[dt] = MFMA32(vf, pf, o[dt]);
        }
        __builtin_amdgcn_s_setprio(0);

        asm volatile("s_waitcnt vmcnt(0)" ::: "memory");   // my stage writes landed
        cur ^= 1;
    }
    __syncthreads();   // all warps done with K/V LDS; safe to reuse as oex

    // ---- epilogue: 4-group split-K merge, two qw passes ----
    if (l4 == 0) {
        mex32[(qw * 4 + g) * 32 + l15]      = m0r;
        mex32[(qw * 4 + g) * 32 + 16 + l15] = m1r;
        lex32[(qw * 4 + g) * 32 + l15]      = l0r;
        lex32[(qw * 4 + g) * 32 + 16 + l15] = l1r;
    }
    __syncthreads();

    float mq = (lane & 16) ? m1r : m0r;
    float mst = -1e30f;
#pragma unroll
    for (int g2 = 0; g2 < 4; ++g2)
        mst = fmaxf(mst, mex32[(qw * 4 + g2) * 32 + l31]);
    float osc = __expf(mq - mst);

#pragma unroll 1
    for (int s = 0; s < 2; ++s) {
        if (qw == s) {
            float* og = oexf + g * (32 * 258);
#pragma unroll
            for (int dt = 0; dt < 8; ++dt)
#pragma unroll
                for (int r = 0; r < 16; ++r) {
                    int d = dt * 32 + (r & 3) + 8 * (r >> 2) + 4 * l5;
                    og[l31 * 258 + d] = o[dt][r] * osc;
                }
        }
        __syncthreads();
        {
            const int q = tid >> 4, dg = tid & 15;
            float mA = mex32[(s * 4 + 0) * 32 + q], mB = mex32[(s * 4 + 1) * 32 + q];
            float mC = mex32[(s * 4 + 2) * 32 + q], mD = mex32[(s * 4 + 3) * 32 + q];
            float ms = fmaxf(fmaxf(mA, mB), fmaxf(mC, mD));
            float lt = lex32[(s * 4 + 0) * 32 + q] * __expf(mA - ms)
                     + lex32[(s * 4 + 1) * 32 + q] * __expf(mB - ms)
                     + lex32[(s * 4 + 2) * 32 + q] * __expf(mC - ms)
                     + lex32[(s * 4 + 3) * 32 + q] * __expf(mD - ms);
            float inv = 1.f / lt;
#pragma unroll
            for (int i = 0; i < 4; ++i) {
                int d0 = dg * 16 + i * 4;
                f32x4 a = *reinterpret_cast<const f32x4*>(oexf + q * 258 + d0);
#pragma unroll
                for (int g2 = 1; g2 < 4; ++g2) {
                    f32x4 t = *reinterpret_cast<const f32x4*>(
                        oexf + g2 * (32 * 258) + q * 258 + d0);
                    a[0] += t[0]; a[1] += t[1]; a[2] += t[2]; a[3] += t[3];
                }
                a[0] *= inv; a[1] *= inv; a[2] *= inv; a[3] *= inv;
                *reinterpret_cast<f32x4*>(
                    outp + base + (size_t)(q0 + s * 32 + q) * Cc + d0) = a;
            }
        }
        __syncthreads();
    }
}

extern "C" void kernel_launch(void* const* d_in, const int* in_sizes, int n_in,
                              void* d_out, int out_size, void* d_ws, size_t ws_size,
                              hipStream_t stream)
{
    (void)in_sizes; (void)n_in; (void)out_size; (void)ws_size;
    const float* x   = (const float*)d_in[0];
    const int*  mask = (const int*)d_in[1];
    const float* Wk  = (const float*)d_in[2];
    const float* Wq  = (const float*)d_in[3];
    const float* Wv  = (const float*)d_in[4];
    float* out = (float*)d_out;

    _Float16* q  = (_Float16*)d_ws;
    _Float16* k  = q + (size_t)BT * Cc;
    _Float16* vt = k + (size_t)BT * Cc;

    dim3 gA(128, 6), blkA(256);
    size_t ldsA = (size_t)(128 + 128) * 264 * sizeof(_Float16);
    qkv_proj<<<gA, blkA, ldsA, stream>>>(x, Wq, Wk, Wv, q, k, vt);

    dim3 gB(256), blkB(512);
    size_t ldsB = 145408;
    attn_kernel<<<gB, blkB, ldsB, stream>>>(q, k, vt, mask, out);
}

// Round 8
// 138.516 us; speedup vs baseline: 17.1220x; 1.0217x over previous
//
#include <hip/hip_runtime.h>

// Round 8: round 7 + conflict-free LDS fragment layouts.
//   kT subtile [kc][chunk][key][8]; vT subtile [dt][khalf][d31][8] -> every b128
//   LDS read has 8 consecutive lanes at 16B stride (all 32 banks). Staging is a
//   linear global_load_lds copy, so the LDS layout == global layout.
// grid 256 (1 blk/CU), 512 thr = 2 qw(32q) x 4 g(16-key groups), ONE barrier/iter.
//   d_in: 0=x f32, 1=mask i32, 2=Wk, 3=Wq, 4=Wv
// ws (f16): qT [BT/32][8192] | kT [BT/16][4096] | vT [BT/16][4096]
//   qT: [(qh*8+kc)*512 + l4*128 + tok*8 + j]  (x1/16 folded)
//   kT: [kc*512 + ch*128 + key*8 + j]   <-> K[16t+key][kc*32+ch*8+j]
//   vT: [dt*512 + kh*256 + d31*8 + j]   <-> V^T[dt*32+d31][16t+kh*8+j]

typedef __attribute__((ext_vector_type(8)))  _Float16 f16x8;
typedef __attribute__((ext_vector_type(4)))  _Float16 f16x4;
typedef __attribute__((ext_vector_type(4)))  float    f32x4;
typedef __attribute__((ext_vector_type(16))) float    f32x16;

constexpr int Bb = 4;
constexpr int Tt = 4096;
constexpr int Cc = 256;
constexpr int BT = Bb * Tt;
constexpr int NI = 64;                 // iters: 4 groups x 16 keys x 64 = 4096

#define MFMA16(a, b, c) __builtin_amdgcn_mfma_f32_16x16x32_f16((a), (b), (c), 0, 0, 0)
#define MFMA32(a, b, c) __builtin_amdgcn_mfma_f32_32x32x16_f16((a), (b), (c), 0, 0, 0)

__device__ __forceinline__ void gl16(const _Float16* gp, char* lp) {
    __builtin_amdgcn_global_load_lds(
        (const __attribute__((address_space(1))) void*)gp,
        (__attribute__((address_space(3))) void*)lp, 16, 0, 0);
}

// ---------------- Kernel A: fused QKV projection ----------------
__global__ __launch_bounds__(256) void qkv_proj(
    const float* __restrict__ x,
    const float* __restrict__ Wq, const float* __restrict__ Wk,
    const float* __restrict__ Wv,
    _Float16* __restrict__ qo, _Float16* __restrict__ ko,
    _Float16* __restrict__ vto)
{
    extern __shared__ _Float16 sm[];
    _Float16* xs = sm;              // [128][264]
    _Float16* wsm = sm + 128 * 264; // [128][264]

    const int tid = threadIdx.x;
    const int m0  = blockIdx.x * 128;
    const int ny  = blockIdx.y;
    const int mat = ny >> 1;              // 0=q 1=k 2=v
    const int d0  = (ny & 1) * 128;
    const float* W = (mat == 0) ? Wq : (mat == 1 ? Wk : Wv);

#pragma unroll
    for (int i = 0; i < 32; ++i) {
        int flat = i * 256 + tid;
        int r = flat >> 6, c4 = (flat & 63) << 2;
        float4 v = *reinterpret_cast<const float4*>(x + (size_t)(m0 + r) * Cc + c4);
        f16x4 h = { (_Float16)v.x, (_Float16)v.y, (_Float16)v.z, (_Float16)v.w };
        *reinterpret_cast<f16x4*>(xs + r * 264 + c4) = h;
    }
#pragma unroll
    for (int i = 0; i < 32; ++i) {
        int flat = i * 256 + tid;
        int r = flat >> 6, c4 = (flat & 63) << 2;
        float4 v = *reinterpret_cast<const float4*>(W + (size_t)(d0 + r) * Cc + c4);
        f16x4 h = { (_Float16)v.x, (_Float16)v.y, (_Float16)v.z, (_Float16)v.w };
        *reinterpret_cast<f16x4*>(wsm + r * 264 + c4) = h;
    }
    __syncthreads();

    const int w = tid >> 6, lane = tid & 63;
    const int lr = lane & 15, lg = lane >> 4;

    f32x4 acc[2][8] = {};

#pragma unroll
    for (int kc = 0; kc < 8; ++kc) {
        const int c0 = kc * 32 + lg * 8;
        f16x8 xf[2], wf[8];
#pragma unroll
        for (int mb = 0; mb < 2; ++mb)
            xf[mb] = *reinterpret_cast<const f16x8*>(xs + (w * 32 + mb * 16 + lr) * 264 + c0);
#pragma unroll
        for (int db = 0; db < 8; ++db)
            wf[db] = *reinterpret_cast<const f16x8*>(wsm + (db * 16 + lr) * 264 + c0);
        if (mat != 2) {
#pragma unroll
            for (int mb = 0; mb < 2; ++mb)
#pragma unroll
                for (int db = 0; db < 8; ++db)
                    acc[mb][db] = MFMA16(wf[db], xf[mb], acc[mb][db]);   // D[d][tok]
        } else {
#pragma unroll
            for (int mb = 0; mb < 2; ++mb)
#pragma unroll
                for (int db = 0; db < 8; ++db)
                    acc[mb][db] = MFMA16(xf[mb], wf[db], acc[mb][db]);   // D[tok][d]
        }
    }

    if (mat != 2) {
        // lane: token m = .. + lr (col), c = d0+db*16+lg*4+reg (row) -> 4 consec c
        const float sc = (mat == 0) ? 0.0625f : 1.0f;
        const int jj  = (lg & 1) * 4;
#pragma unroll
        for (int mb = 0; mb < 2; ++mb)
#pragma unroll
            for (int db = 0; db < 8; ++db) {
                int m  = m0 + w * 32 + mb * 16 + lr;
                int c  = d0 + db * 16 + lg * 4;
                int kc = c >> 5;
                int ch = (c >> 3) & 3;
                f32x4 a = acc[mb][db];
                f16x4 h = { (_Float16)(a.x * sc), (_Float16)(a.y * sc),
                            (_Float16)(a.z * sc), (_Float16)(a.w * sc) };
                if (mat == 0) {
                    size_t off = (size_t)(m >> 5) * 8192 + (((m >> 4) & 1) * 8 + kc) * 512
                               + ch * 128 + (m & 15) * 8 + jj;
                    *reinterpret_cast<f16x4*>(qo + off) = h;
                } else {
                    size_t off = (size_t)(m >> 4) * 4096 + kc * 512
                               + ch * 128 + (m & 15) * 8 + jj;
                    *reinterpret_cast<f16x4*>(ko + off) = h;
                }
            }
    } else {
        // lane: d = d0+db*16+lr (col), key m = ..+lg*4+reg (row) -> 4 consec keys
        const int jj = (lg & 1) * 4;
        const int kh = (lg >> 1) & 1;
#pragma unroll
        for (int mb = 0; mb < 2; ++mb)
#pragma unroll
            for (int db = 0; db < 8; ++db) {
                int d = d0 + db * 16 + lr;
                int m = m0 + w * 32 + mb * 16 + lg * 4;
                f32x4 a = acc[mb][db];
                f16x4 h = { (_Float16)a.x, (_Float16)a.y, (_Float16)a.z, (_Float16)a.w };
                size_t off = (size_t)(m >> 4) * 4096 + (d >> 5) * 512
                           + kh * 256 + (d & 31) * 8 + jj;
                *reinterpret_cast<f16x4*>(vto + off) = h;
            }
    }
}

// ---------------- Kernel B: flash attention ----------------
// LDS map (bytes): [0,131072)   2 x [4 g][K 8KB | V 8KB] double buffer
//                  [131072,143360) per-warp P [8][32][24] f16
//                  [143360,144384) mex f32[2][4][32]; [144384,145408) lex
// epilogue reuses [0,132096) as oex f32[4][32][258]
__global__ __launch_bounds__(512, 2) void attn_kernel(
    const _Float16* __restrict__ qb, const _Float16* __restrict__ kb,
    const _Float16* __restrict__ vtb, const int* __restrict__ mask,
    float* __restrict__ outp)
{
    extern __shared__ char smraw[];
    float* mex32 = (float*)(smraw + 143360);
    float* lex32 = (float*)(smraw + 144384);
    float* oexf  = (float*)smraw;

    const int tid = threadIdx.x, w = tid >> 6, lane = tid & 63;
    const int qw = w >> 2, g = w & 3;
    const int l15 = lane & 15, l4 = lane >> 4;
    const int l31 = lane & 31, l5 = lane >> 5;

    const int bid = blockIdx.x;
    const int b   = (bid & 7) >> 1;                    // batch -> XCD pair
    const int qt  = ((bid >> 3) << 1) | (bid & 1);     // [0,64)
    const int q0  = qt * 64;
    const size_t base = (size_t)b * Tt * Cc;
    const int* maskb = mask + (size_t)b * Tt;
    const _Float16* kTb = kb + base;
    const _Float16* vTb = vtb + base;

    // Q fragments: Q[q0 + qw*32 + qh*16 + l15][kc*32 + l4*8 + j]
    f16x8 qf[2][8];
    {
        const _Float16* qTb = qb + (size_t)(b * 128 + qt * 2 + qw) * 8192;
#pragma unroll
        for (int qh = 0; qh < 2; ++qh)
#pragma unroll
            for (int kc = 0; kc < 8; ++kc)
                qf[qh][kc] = *reinterpret_cast<const f16x8*>(
                    qTb + (qh * 8 + kc) * 512 + l4 * 128 + l15 * 8);
    }

    _Float16* pw = (_Float16*)(smraw + 131072) + w * 768;   // [32][24]

    f32x16 o[8] = {};                  // O^T[d = dt*32+(r&3)+8*(r>>2)+4*l5][q=l31]
    float m0r = -60.f, m1r = -60.f, l0r = 0.f, l1r = 0.f;

    // staging: warp (qw,g): qw0 -> K of group g, qw1 -> V of group g (linear copy)
    auto STAGE = [&](int i, int buf) {
        const int kt = i * 4 + g;
        char* dst = smraw + buf * 65536 + g * 16384 + (qw ? 8192 : 0);
        const _Float16* src = (qw ? vTb : kTb) + (size_t)kt * 4096 + lane * 8;
#pragma unroll
        for (int j = 0; j < 8; ++j)
            gl16(src + j * 512, dst + j * 1024);
    };

    STAGE(0, 0);
    asm volatile("s_waitcnt vmcnt(0)" ::: "memory");

    int cur = 0;
#pragma unroll 1
    for (int i = 0; i < NI; ++i) {
        __syncthreads();                       // everyone at iter i; buf cur ready
        if (i + 1 < NI) STAGE(i + 1, cur ^ 1); // flies under compute

        const _Float16* kb_ = (const _Float16*)(smraw + cur * 65536 + g * 16384);
        const _Float16* vb_ = kb_ + 4096;
        int4 mc = *reinterpret_cast<const int4*>(maskb + (i * 4 + g) * 16 + l4 * 4);

        // S^T = K Q^T : D[key = l4*4 + r][q = qh*16 + l15]
        f32x4 s40 = { 0.f, 0.f, 0.f, 0.f }, s41 = { 0.f, 0.f, 0.f, 0.f };
        __builtin_amdgcn_s_setprio(1);
#pragma unroll
        for (int kc = 0; kc < 8; ++kc) {
            f16x8 kf = *reinterpret_cast<const f16x8*>(kb_ + kc * 512 + l4 * 128 + l15 * 8);
            s40 = MFMA16(kf, qf[0][kc], s40);
            s41 = MFMA16(kf, qf[1][kc], s41);
        }
        __builtin_amdgcn_s_setprio(0);

        if (mc.x == 0) { s40[0] = -1e30f; s41[0] = -1e30f; }
        if (mc.y == 0) { s40[1] = -1e30f; s41[1] = -1e30f; }
        if (mc.z == 0) { s40[2] = -1e30f; s41[2] = -1e30f; }
        if (mc.w == 0) { s40[3] = -1e30f; s41[3] = -1e30f; }

        // online softmax per qh (q = l15; keys across l4 groups)
        float t0 = fmaxf(fmaxf(s40[0], s40[1]), fmaxf(s40[2], s40[3]));
        float t1 = fmaxf(fmaxf(s41[0], s41[1]), fmaxf(s41[2], s41[3]));
        t0 = fmaxf(t0, __shfl_xor(t0, 16, 64)); t0 = fmaxf(t0, __shfl_xor(t0, 32, 64));
        t1 = fmaxf(t1, __shfl_xor(t1, 16, 64)); t1 = fmaxf(t1, __shfl_xor(t1, 32, 64));

        if (__any(t0 > m0r + 8.f || t1 > m1r + 8.f)) {     // defer-max
            float mn0 = fmaxf(m0r, t0), mn1 = fmaxf(m1r, t1);
            float c0 = __expf(m0r - mn0), c1 = __expf(m1r - mn1);
            m0r = mn0; m1r = mn1; l0r *= c0; l1r *= c1;
            float cs = (lane & 16) ? c1 : c0;              // o cols: q = l31
#pragma unroll
            for (int dt = 0; dt < 8; ++dt) o[dt] *= cs;
        }

        float rs0 = 0.f, rs1 = 0.f;
#pragma unroll
        for (int r = 0; r < 4; ++r) {
            float p0 = __expf(s40[r] - m0r); s40[r] = p0; rs0 += p0;
            float p1 = __expf(s41[r] - m1r); s41[r] = p1; rs1 += p1;
        }
        rs0 += __shfl_xor(rs0, 16, 64); rs0 += __shfl_xor(rs0, 32, 64);
        rs1 += __shfl_xor(rs1, 16, 64); rs1 += __shfl_xor(rs1, 32, 64);
        l0r += rs0; l1r += rs1;

        // P -> pw[q][k] f16; reread as PV B-frag (in-wave RAW, lgkm-ordered)
        {
            f16x4 h0 = { (_Float16)s40[0], (_Float16)s40[1], (_Float16)s40[2], (_Float16)s40[3] };
            f16x4 h1 = { (_Float16)s41[0], (_Float16)s41[1], (_Float16)s41[2], (_Float16)s41[3] };
            *reinterpret_cast<f16x4*>(pw + l15 * 24 + l4 * 4)        = h0;
            *reinterpret_cast<f16x4*>(pw + (16 + l15) * 24 + l4 * 4) = h1;
        }
        f16x8 pf = *reinterpret_cast<const f16x8*>(pw + l31 * 24 + l5 * 8);

        // O^T += V^T P^T  (32x32x16, K=16 keys)
        __builtin_amdgcn_s_setprio(1);
#pragma unroll
        for (int dt = 0; dt < 8; ++dt) {
            f16x8 vf = *reinterpret_cast<const f16x8*>(vb_ + dt * 512 + l5 * 256 + l31 * 8);
            o[dt] = MFMA32(vf, pf, o[dt]);
        }
        __builtin_amdgcn_s_setprio(0);

        asm volatile("s_waitcnt vmcnt(0)" ::: "memory");   // my stage writes landed
        cur ^= 1;
    }
    __syncthreads();   // all warps done with K/V LDS; safe to reuse as oex

    // ---- epilogue: 4-group split-K merge, two qw passes ----
    if (l4 == 0) {
        mex32[(qw * 4 + g) * 32 + l15]      = m0r;
        mex32[(qw * 4 + g) * 32 + 16 + l15] = m1r;
        lex32[(qw * 4 + g) * 32 + l15]      = l0r;
        lex32[(qw * 4 + g) * 32 + 16 + l15] = l1r;
    }
    __syncthreads();

    float mq = (lane & 16) ? m1r : m0r;
    float mst = -1e30f;
#pragma unroll
    for (int g2 = 0; g2 < 4; ++g2)
        mst = fmaxf(mst, mex32[(qw * 4 + g2) * 32 + l31]);
    float osc = __expf(mq - mst);

#pragma unroll 1
    for (int s = 0; s < 2; ++s) {
        if (qw == s) {
            float* og = oexf + g * (32 * 258);
#pragma unroll
            for (int dt = 0; dt < 8; ++dt)
#pragma unroll
                for (int r = 0; r < 16; ++r) {
                    int d = dt * 32 + (r & 3) + 8 * (r >> 2) + 4 * l5;
                    og[l31 * 258 + d] = o[dt][r] * osc;
                }
        }
        __syncthreads();
        {
            const int q = tid >> 4, dg = tid & 15;
            float mA = mex32[(s * 4 + 0) * 32 + q], mB = mex32[(s * 4 + 1) * 32 + q];
            float mC = mex32[(s * 4 + 2) * 32 + q], mD = mex32[(s * 4 + 3) * 32 + q];
            float ms = fmaxf(fmaxf(mA, mB), fmaxf(mC, mD));
            float lt = lex32[(s * 4 + 0) * 32 + q] * __expf(mA - ms)
                     + lex32[(s * 4 + 1) * 32 + q] * __expf(mB - ms)
                     + lex32[(s * 4 + 2) * 32 + q] * __expf(mC - ms)
                     + lex32[(s * 4 + 3) * 32 + q] * __expf(mD - ms);
            float inv = 1.f / lt;
#pragma unroll
            for (int i = 0; i < 4; ++i) {
                int d0 = dg * 16 + i * 4;
                f32x4 a = *reinterpret_cast<const f32x4*>(oexf + q * 258 + d0);
#pragma unroll
                for (int g2 = 1; g2 < 4; ++g2) {
                    f32x4 t = *reinterpret_cast<const f32x4*>(
                        oexf + g2 * (32 * 258) + q * 258 + d0);
                    a[0] += t[0]; a[1] += t[1]; a[2] += t[2]; a[3] += t[3];
                }
                a[0] *= inv; a[1] *= inv; a[2] *= inv; a[3] *= inv;
                *reinterpret_cast<f32x4*>(
                    outp + base + (size_t)(q0 + s * 32 + q) * Cc + d0) = a;
            }
        }
        __syncthreads();
    }
}

extern "C" void kernel_launch(void* const* d_in, const int* in_sizes, int n_in,
                              void* d_out, int out_size, void* d_ws, size_t ws_size,
                              hipStream_t stream)
{
    (void)in_sizes; (void)n_in; (void)out_size; (void)ws_size;
    const float* x   = (const float*)d_in[0];
    const int*  mask = (const int*)d_in[1];
    const float* Wk  = (const float*)d_in[2];
    const float* Wq  = (const float*)d_in[3];
    const float* Wv  = (const float*)d_in[4];
    float* out = (float*)d_out;

    _Float16* q  = (_Float16*)d_ws;
    _Float16* k  = q + (size_t)BT * Cc;
    _Float16* vt = k + (size_t)BT * Cc;

    dim3 gA(128, 6), blkA(256);
    size_t ldsA = (size_t)(128 + 128) * 264 * sizeof(_Float16);
    qkv_proj<<<gA, blkA, ldsA, stream>>>(x, Wq, Wk, Wv, q, k, vt);

    dim3 gB(256), blkB(512);
    size_t ldsB = 145408;
    attn_kernel<<<gB, blkB, ldsB, stream>>>(q, k, vt, mask, out);
}